// Round 6
// baseline (213.464 us; speedup 1.0000x reference)
//
#include <hip/hip_runtime.h>

// Problem constants (from reference): org/enh [32,3,512,512] fp32.
#define NB 32
#define NC 3
#define NH 512
#define NW 512
#define PH 128   // NH/4
#define PW 128   // NW/4
#define NPOOL  (NB * PH * PW)     // 524288 pooled elements
#define NPLANE (NB * NC)          // 96 (b,c) planes
#define PLANE_ELEMS (PH * PW)     // 16384 per partial plane
#define NITEMS (NPLANE * PLANE_ELEMS)  // 1,572,864 partial elements (6 MB)
#define NBLK_A (NPLANE * 128)     // 12288 blocks: 4 image rows (8 KB) each
#define NBLK_RED (NPOOL / 256)    // 2048

typedef float vf4 __attribute__((ext_vector_type(4)));

// Stage A: memcpy-shaped pool. Thread t of the grid loads float4 #t of each
// input — ONE load per stream per thread, globally linear (block b covers
// bytes [b*8K,(b+1)*8K) = exactly 4 image rows of one (b,c) plane). This is
// address-identical to the 6.87 TB/s fill/copy the harness runs in the same
// window. The 4-row vertical pool is a small LDS reduce: lane t reads
// smem[t], [t+128], [t+256], [t+384] — all bank t%32, 2 lanes/bank = free.
// VGPR ~16 -> 8 waves/SIMD; 12288 blocks; pure TLP streaming (no per-thread
// gather — R2/R3/R5's row-strided 8-load gather plateaued at ~3.7 TB/s).
__global__ __launch_bounds__(512) void stageA_pool_kernel(
    const vf4* __restrict__ o4, const vf4* __restrict__ e4,
    float* __restrict__ partial)
{
    __shared__ float smem[512];
    int t = threadIdx.x;
    int g = blockIdx.x * 512 + t;       // global float4 index, linear sweep

    vf4 o = o4[g];
    vf4 e = e4[g];
    vf4 d = o - e;
    smem[t] = (d.x + d.y) + (d.z + d.w);   // 4-wide horizontal = pool width
    __syncthreads();

    if (t < 128) {
        float v = (smem[t] + smem[t + 128]) + (smem[t + 256] + smem[t + 384]);
        int plane = blockIdx.x >> 7;        // (b,c) plane 0..95
        int prow  = blockIdx.x & 127;       // pooled row 0..127
        partial[plane * PLANE_ELEMS + prow * PW + t] = v * (1.0f / 48.0f);
    }
}

// Stage B: shift-difference sum-of-squares with inline channel-plane sum.
// pooled[b,y,x] = sum_c partial[(3b+c),y,x]; 6 MB working set, L2/L3-resident.
// Per-block partials to ws (no single-address atomics across XCDs).
__global__ __launch_bounds__(256) void spa_reduce_kernel(
    const float* __restrict__ partial, float* __restrict__ partials_out)
{
    int idx = blockIdx.x * blockDim.x + threadIdx.x;
    int pw = idx & (PW - 1);
    int ph = (idx >> 7) & (PH - 1);
    int b  = idx >> 14;

    const float* p0 = partial + (b * 3 + 0) * PLANE_ELEMS;
    const float* p1 = partial + (b * 3 + 1) * PLANE_ELEMS;
    const float* p2 = partial + (b * 3 + 2) * PLANE_ELEMS;

    #define POOLED(y, x) (p0[(y) * PW + (x)] + p1[(y) * PW + (x)] + p2[(y) * PW + (x)])
    float c = POOLED(ph, pw);
    float l = (pw > 0)      ? POOLED(ph, pw - 1) : 0.f;
    float r = (pw < PW - 1) ? POOLED(ph, pw + 1) : 0.f;
    float u = (ph > 0)      ? POOLED(ph - 1, pw) : 0.f;
    float d = (ph < PH - 1) ? POOLED(ph + 1, pw) : 0.f;
    #undef POOLED

    float dl = c - l, dr = c - r, du = c - u, dd = c - d;
    float s = (dl * dl + dr * dr) + (du * du + dd * dd);

#pragma unroll
    for (int off = 32; off > 0; off >>= 1)
        s += __shfl_down(s, off, 64);

    __shared__ float smem[4];
    int lane = threadIdx.x & 63;
    int wid  = threadIdx.x >> 6;
    if (lane == 0) smem[wid] = s;
    __syncthreads();
    if (threadIdx.x == 0)
        partials_out[blockIdx.x] = (smem[0] + smem[1]) + (smem[2] + smem[3]);
}

// Stage C: single block folds 2048 partials -> final mean, writes d_out.
__global__ __launch_bounds__(256) void final_reduce_kernel(
    const float* __restrict__ partials, float* __restrict__ out)
{
    float s = 0.f;
#pragma unroll
    for (int i = 0; i < NBLK_RED / 256; ++i)
        s += partials[i * 256 + threadIdx.x];

#pragma unroll
    for (int off = 32; off > 0; off >>= 1)
        s += __shfl_down(s, off, 64);

    __shared__ float smem[4];
    int lane = threadIdx.x & 63;
    int wid  = threadIdx.x >> 6;
    if (lane == 0) smem[wid] = s;
    __syncthreads();
    if (threadIdx.x == 0)
        out[0] = ((smem[0] + smem[1]) + (smem[2] + smem[3])) * (1.0f / (float)NPOOL);
}

extern "C" void kernel_launch(void* const* d_in, const int* in_sizes, int n_in,
                              void* d_out, int out_size, void* d_ws, size_t ws_size,
                              hipStream_t stream) {
    const vf4* o4 = (const vf4*)d_in[0];
    const vf4* e4 = (const vf4*)d_in[1];
    float* out = (float*)d_out;
    float* partial      = (float*)d_ws;                 // 6 MB: [96][128][128]
    float* blockpartial = (float*)d_ws + NITEMS;        // + 8 KB

    stageA_pool_kernel<<<NBLK_A, 512, 0, stream>>>(o4, e4, partial);
    spa_reduce_kernel<<<NBLK_RED, 256, 0, stream>>>(partial, blockpartial);
    final_reduce_kernel<<<1, 256, 0, stream>>>(blockpartial, out);
}

// Round 7
// 196.725 us; speedup vs baseline: 1.0851x; 1.0851x over previous
//
#include <hip/hip_runtime.h>

// Problem constants (from reference): org/enh [32,3,512,512] fp32.
#define NB 32
#define NC 3
#define NH 512
#define NW 512
#define PH 128   // NH/4
#define PW 128   // NW/4
#define NPOOL  (NB * PH * PW)     // 524288 pooled elements
#define NPLANE (NB * NC)          // 96 (b,c) planes
#define PLANE_ELEMS (PH * PW)     // 16384 per partial plane
#define NITEMS (NPLANE * PLANE_ELEMS)  // 1,572,864 stage-A work items
#define NBLK_A 1024
#define ITEMS_A 6                 // 1024*256*6 == NITEMS exactly
#define STRIDE_A (NBLK_A * 256)   // 262144
#define NBLK_RED (NPOOL / 256)    // 2048

typedef float vf4 __attribute__((ext_vector_type(4)));

// item -> float4 base index in a [96][512][128] float4 layout:
// plane = item>>14, pooled row = (item>>7)&127 (covers image rows 4r..4r+3),
// x4 = item&127.
__device__ __forceinline__ int item_base(int item) {
    return ((item >> 14) << 16) + (((item >> 7) & 127) << 9) + (item & 127);
}

// Stage A: per-channel fused 4x4 avgpool of (org - enh), deep software
// pipeline. Evidence R2..R6: addressing shape (linear vs 2KB-strided) is
// irrelevant; per-thread pipelined MLP is the only lever that moved stageA
// (70 -> ~55 us). R5 was only 3 iterations deep -> prologue latency was 1/3
// of thread lifetime. This version: 6 items/thread, register double-buffer
// (8 loads in flight while computing), 1024 blocks (~16 waves/CU at ~100
// VGPR). Exposed latency amortizes to 1/6.
__global__ __launch_bounds__(256) void stageA_pool_kernel(
    const vf4* __restrict__ o4, const vf4* __restrict__ e4,
    float* __restrict__ partial)
{
    int item = blockIdx.x * 256 + threadIdx.x;

    int base = item_base(item);
    vf4 oc0 = __builtin_nontemporal_load(o4 + base);
    vf4 oc1 = __builtin_nontemporal_load(o4 + base + 128);
    vf4 oc2 = __builtin_nontemporal_load(o4 + base + 256);
    vf4 oc3 = __builtin_nontemporal_load(o4 + base + 384);
    vf4 ec0 = __builtin_nontemporal_load(e4 + base);
    vf4 ec1 = __builtin_nontemporal_load(e4 + base + 128);
    vf4 ec2 = __builtin_nontemporal_load(e4 + base + 256);
    vf4 ec3 = __builtin_nontemporal_load(e4 + base + 384);

#pragma unroll
    for (int it = 0; it < ITEMS_A; ++it) {
        vf4 on0, on1, on2, on3, en0, en1, en2, en3;
        if (it < ITEMS_A - 1) {
            int nbase = item_base(item + STRIDE_A);
            on0 = __builtin_nontemporal_load(o4 + nbase);
            on1 = __builtin_nontemporal_load(o4 + nbase + 128);
            on2 = __builtin_nontemporal_load(o4 + nbase + 256);
            on3 = __builtin_nontemporal_load(o4 + nbase + 384);
            en0 = __builtin_nontemporal_load(e4 + nbase);
            en1 = __builtin_nontemporal_load(e4 + nbase + 128);
            en2 = __builtin_nontemporal_load(e4 + nbase + 256);
            en3 = __builtin_nontemporal_load(e4 + nbase + 384);
        }

        vf4 d = ((oc0 - ec0) + (oc1 - ec1)) + ((oc2 - ec2) + (oc3 - ec3));
        float v = (d.x + d.y) + (d.z + d.w);
        partial[item] = v * (1.0f / 48.0f);   // /3 channels /16 pool window

        if (it < ITEMS_A - 1) {
            oc0 = on0; oc1 = on1; oc2 = on2; oc3 = on3;
            ec0 = en0; ec1 = en1; ec2 = en2; ec3 = en3;
            item += STRIDE_A;
        }
    }
}

// Stage B: shift-difference sum-of-squares with inline channel-plane sum.
// pooled[b,y,x] = sum_c partial[(3b+c),y,x]; 6 MB working set, L2/L3-resident.
// Per-block partials to ws (no single-address atomics across XCDs).
__global__ __launch_bounds__(256) void spa_reduce_kernel(
    const float* __restrict__ partial, float* __restrict__ partials_out)
{
    int idx = blockIdx.x * blockDim.x + threadIdx.x;
    int pw = idx & (PW - 1);
    int ph = (idx >> 7) & (PH - 1);
    int b  = idx >> 14;

    const float* p0 = partial + (b * 3 + 0) * PLANE_ELEMS;
    const float* p1 = partial + (b * 3 + 1) * PLANE_ELEMS;
    const float* p2 = partial + (b * 3 + 2) * PLANE_ELEMS;

    #define POOLED(y, x) (p0[(y) * PW + (x)] + p1[(y) * PW + (x)] + p2[(y) * PW + (x)])
    float c = POOLED(ph, pw);
    float l = (pw > 0)      ? POOLED(ph, pw - 1) : 0.f;
    float r = (pw < PW - 1) ? POOLED(ph, pw + 1) : 0.f;
    float u = (ph > 0)      ? POOLED(ph - 1, pw) : 0.f;
    float d = (ph < PH - 1) ? POOLED(ph + 1, pw) : 0.f;
    #undef POOLED

    float dl = c - l, dr = c - r, du = c - u, dd = c - d;
    float s = (dl * dl + dr * dr) + (du * du + dd * dd);

#pragma unroll
    for (int off = 32; off > 0; off >>= 1)
        s += __shfl_down(s, off, 64);

    __shared__ float smem[4];
    int lane = threadIdx.x & 63;
    int wid  = threadIdx.x >> 6;
    if (lane == 0) smem[wid] = s;
    __syncthreads();
    if (threadIdx.x == 0)
        partials_out[blockIdx.x] = (smem[0] + smem[1]) + (smem[2] + smem[3]);
}

// Stage C: single block folds 2048 partials -> final mean, writes d_out.
__global__ __launch_bounds__(256) void final_reduce_kernel(
    const float* __restrict__ partials, float* __restrict__ out)
{
    float s = 0.f;
#pragma unroll
    for (int i = 0; i < NBLK_RED / 256; ++i)
        s += partials[i * 256 + threadIdx.x];

#pragma unroll
    for (int off = 32; off > 0; off >>= 1)
        s += __shfl_down(s, off, 64);

    __shared__ float smem[4];
    int lane = threadIdx.x & 63;
    int wid  = threadIdx.x >> 6;
    if (lane == 0) smem[wid] = s;
    __syncthreads();
    if (threadIdx.x == 0)
        out[0] = ((smem[0] + smem[1]) + (smem[2] + smem[3])) * (1.0f / (float)NPOOL);
}

extern "C" void kernel_launch(void* const* d_in, const int* in_sizes, int n_in,
                              void* d_out, int out_size, void* d_ws, size_t ws_size,
                              hipStream_t stream) {
    const vf4* o4 = (const vf4*)d_in[0];
    const vf4* e4 = (const vf4*)d_in[1];
    float* out = (float*)d_out;
    float* partial      = (float*)d_ws;                 // 6 MB: [96][128][128]
    float* blockpartial = (float*)d_ws + NITEMS;        // + 8 KB

    stageA_pool_kernel<<<NBLK_A, 256, 0, stream>>>(o4, e4, partial);
    spa_reduce_kernel<<<NBLK_RED, 256, 0, stream>>>(partial, blockpartial);
    final_reduce_kernel<<<1, 256, 0, stream>>>(blockpartial, out);
}